// Round 3
// baseline (2125.820 us; speedup 1.0000x reference)
//
#include <hip/hip_runtime.h>
#include <hip/hip_bf16.h>
#include <math.h>

#define KIMG 8
#define HH 128
#define WW 128
#define NTOK (HH*WW)
#define DD 768
#define CC 10
#define NITER 5
#define GMAX 128

// ---------- wave helpers ----------
__device__ __forceinline__ float rl_f(float x, int l){
  return __int_as_float(__builtin_amdgcn_readlane(__float_as_int(x), l));
}
template<int CTRL,int RMASK>
__device__ __forceinline__ float dppadd(float x){
  int y = __builtin_amdgcn_update_dpp(0, __float_as_int(x), CTRL, RMASK, 0xf, true);
  return x + __int_as_float(y);
}
// full-wave sum; total lands in lane 63
__device__ __forceinline__ float wredsum(float x){
  x = dppadd<0x111,0xf>(x);
  x = dppadd<0x112,0xf>(x);
  x = dppadd<0x114,0xf>(x);
  x = dppadd<0x118,0xf>(x);
  x = dppadd<0x142,0xa>(x);
  x = dppadd<0x143,0xc>(x);
  return x;
}
__device__ __forceinline__ float read_dim_f(const int* p){
  int v = *p;
  if (v > 0 && v < (1<<20)) return (float)v;   // plausible integer
  return __int_as_float(v);                    // else float bits
}

union F4 { float4 v; float f[4]; };

// ---------- 1. compact valid token indices (deterministic order) ----------
__global__ __launch_bounds__(256) void compact_kernel(const float* __restrict__ mask,
    int* __restrict__ vidx, int* __restrict__ vcnt){
  int k = blockIdx.x, tid = threadIdx.x;
  __shared__ int s[256];
  const float* mk = mask + (size_t)k*NTOK;
  int base = tid*64, c = 0;
  for (int j=0;j<64;j++) c += (mk[base+j] > 0.f) ? 1 : 0;
  s[tid] = c; __syncthreads();
  for (int st=1; st<256; st<<=1){
    int v = s[tid]; int u = (tid>=st) ? s[tid-st] : 0;
    __syncthreads(); s[tid] = v+u; __syncthreads();
  }
  int off = s[tid] - c;          // exclusive prefix
  if (tid==255) vcnt[k] = s[255];
  int* vk = vidx + (size_t)k*NTOK;
  for (int j=0;j<64;j++){ if (mk[base+j] > 0.f) vk[off++] = base+j; }
}

// ---------- 2. initial centroids = tokens[init_idx] ----------
__global__ __launch_bounds__(256) void init_kernel(const float* __restrict__ feat,
  const float* __restrict__ boxes, const float* __restrict__ Wp, const float* __restrict__ bp,
  const int* __restrict__ iidx, const int* __restrict__ prawh, const int* __restrict__ praww,
  float* __restrict__ cent){
  int k = blockIdx.x, tid = threadIdx.x;
  float top = boxes[k*4+0], lft = boxes[k*4+1], bot = boxes[k*4+2], rgt = boxes[k*4+3];
  float rh = read_dim_f(prawh), rw = read_dim_f(praww);
  float inv_rw = 1.f/(rw-1.f), inv_rh = 1.f/(rh-1.f);
  float xs = (rgt-lft)*(1.f/(float)WW), ys = (bot-top)*(1.f/(float)HH);
  for (int c=0;c<CC;c++){
    int tok = iidx[k*CC+c];
    int h = tok>>7, w = tok&127;
    float xg = fminf(fmaxf(((float)w*xs+lft)*inv_rw,0.f),1.f);
    float yg = fminf(fmaxf(((float)h*ys+top)*inv_rh,0.f),1.f);
    const float* fp = feat + ((size_t)k*NTOK + tok)*DD;
    float* cp = cent + ((size_t)k*CC + c)*DD;
    for (int d=tid; d<DD; d+=256)
      cp[d] = fp[d] + xg*Wp[d] + yg*Wp[DD+d] + bp[d];
  }
}

// ---------- 2b. per-cluster scalars: sA=||c||^2-2bp.c, sW0=-2Wp0.c, sW1=-2Wp1.c ----------
__global__ __launch_bounds__(64) void scalar_kernel(const float* __restrict__ cent,
  const float* __restrict__ Wp, const float* __restrict__ bp, float* __restrict__ scal){
  int c = blockIdx.x, k = blockIdx.y, lane = threadIdx.x;
  const float* cp = cent + ((size_t)k*CC+c)*DD;
  float a0=0.f,a1=0.f,ab=0.f,an=0.f;
  #pragma unroll
  for (int j=0;j<12;j++){
    float cv = cp[j*64+lane];
    a0=fmaf(cv,Wp[j*64+lane],a0);
    a1=fmaf(cv,Wp[DD+j*64+lane],a1);
    ab=fmaf(cv,bp[j*64+lane],ab);
    an=fmaf(cv,cv,an);
  }
  a0=wredsum(a0); a1=wredsum(a1); ab=wredsum(ab); an=wredsum(an);
  if (lane==63){
    float* o = scal + ((size_t)k*CC+c)*4;
    o[0]=fmaf(-2.f,ab,an); o[1]=-2.f*a0; o[2]=-2.f*a1; o[3]=0.f;
  }
}

// ---------- 3. assignment + per-block partial sums (hot) ----------
// lane owns dims d = 256*j + 4*lane + m. Centroids staged in LDS, read per
// cluster as 3x ds_read_b128 shared across a 4-token quad. Token indices for
// a wave live in ONE VGPR (lane-indexed), fetched via v_readlane.
__global__ __attribute__((amdgpu_flat_work_group_size(256,256), amdgpu_waves_per_eu(2,2)))
void assign_kernel(
    const float* __restrict__ feat, const float* __restrict__ boxes,
    const int* __restrict__ prawh, const int* __restrict__ praww,
    const float* __restrict__ cent, const float* __restrict__ scal,
    const int* __restrict__ vidx, const int* __restrict__ vcnt,
    float* __restrict__ fsums, float* __restrict__ osxg, float* __restrict__ osyg,
    int* __restrict__ ocnt, int G)
{
  int g = blockIdx.x, k = blockIdx.y;
  int tid = threadIdx.x, lane = tid & 63, wv = tid >> 6;
  __shared__ float s_cent[CC*DD];
  __shared__ float s_sums[CC*DD];
  __shared__ float s_sxg[16], s_syg[16];
  __shared__ int   s_cnt[16];
  const float* ck = cent + (size_t)k*CC*DD;
  for (int x=tid;x<CC*DD;x+=256){ s_cent[x]=ck[x]; s_sums[x]=0.f; }
  if (tid<16){ s_sxg[tid]=0.f; s_syg[tid]=0.f; s_cnt[tid]=0; }
  __syncthreads();

  // per-cluster scalars: uniform loads -> SGPRs
  float sA[CC], sW0[CC], sW1[CC];
  #pragma unroll
  for (int c=0;c<CC;c++){
    const float* sp = scal + ((size_t)k*CC+c)*4;
    sA[c]=sp[0]; sW0[c]=sp[1]; sW1[c]=sp[2];
  }

  float top=boxes[k*4+0], lft=boxes[k*4+1], bot=boxes[k*4+2], rgt=boxes[k*4+3];
  float rh = read_dim_f(prawh), rw = read_dim_f(praww);
  float inv_rw = 1.f/(rw-1.f), inv_rh = 1.f/(rh-1.f);
  float xs = (rgt-lft)*(1.f/(float)WW), ys = (bot-top)*(1.f/(float)HH);

  int count = vcnt[k];
  int nw = G*4;
  int wid = g*4 + wv;
  int cbeg = (int)(((long long)count * wid) / nw);
  int cend = (int)(((long long)count * (wid+1)) / nw);
  const int* vk = vidx + (size_t)k*NTOK;
  const float* featk = feat + (size_t)k*NTOK*DD;

  for (int seg = cbeg; seg < cend; seg += 64){
    int send = min(seg+64, cend);
    int nseg = send - seg;
    int vkq = vk[seg + min(lane, nseg-1)];   // wave's token indices, lane-held

    for (int q=0; q<nseg; q+=4){
      F4 buf[4][3]; float xg[4], yg[4];
      #pragma unroll
      for (int t=0;t<4;t++){
        int ridx = min(q+t, nseg-1);
        int tok = __builtin_amdgcn_readlane(vkq, ridx);   // SGPR token index
        const float* fp = featk + (size_t)tok*DD + 4*lane;
        buf[t][0].v = *(const float4*)(fp);
        buf[t][1].v = *(const float4*)(fp+256);
        buf[t][2].v = *(const float4*)(fp+512);
        int h = tok>>7, w = tok&127;
        xg[t] = fminf(fmaxf(((float)w*xs+lft)*inv_rw,0.f),1.f);
        yg[t] = fminf(fmaxf(((float)h*ys+top)*inv_rh,0.f),1.f);
      }

      float acc[4][CC];
      #pragma unroll
      for (int t=0;t<4;t++)
        #pragma unroll
        for (int c=0;c<CC;c++) acc[t][c]=0.f;

      #pragma unroll
      for (int c=0;c<CC;c++){
        F4 cs0, cs1, cs2;
        const float* cp = s_cent + c*DD + 4*lane;
        cs0.v = *(const float4*)(cp);
        cs1.v = *(const float4*)(cp+256);
        cs2.v = *(const float4*)(cp+512);
        #pragma unroll
        for (int t=0;t<4;t++)
          #pragma unroll
          for (int m=0;m<4;m++){
            acc[t][c]=fmaf(buf[t][0].f[m],cs0.f[m],acc[t][c]);
            acc[t][c]=fmaf(buf[t][1].f[m],cs1.f[m],acc[t][c]);
            acc[t][c]=fmaf(buf[t][2].f[m],cs2.f[m],acc[t][c]);
          }
      }

      #pragma unroll
      for (int t=0;t<4;t++){
        float best=3.4e38f; int bl=0;
        #pragma unroll
        for (int c=0;c<CC;c++){
          float dot = rl_f(wredsum(acc[t][c]), 63);
          float sc = fmaf(xg[t],sW0[c], fmaf(yg[t],sW1[c], sA[c]));
          sc = fmaf(-2.f, dot, sc);
          if (sc < best){ best=sc; bl=c; }
        }
        bl = __builtin_amdgcn_readfirstlane(bl);
        if (q+t < nseg){                      // uniform predicate
          float* sb = s_sums + bl*DD + lane;  // physical p = j*256+m*64+lane
          #pragma unroll
          for (int j=0;j<3;j++)
            #pragma unroll
            for (int m=0;m<4;m++)
              atomicAdd(&sb[j*256 + m*64], buf[t][j].f[m]);
          if (lane==0){
            atomicAdd(&s_cnt[bl],1);
            atomicAdd(&s_sxg[bl],xg[t]);
            atomicAdd(&s_syg[bl],yg[t]);
          }
        }
      }
    }
  }
  __syncthreads();

  float* fo = fsums + ((size_t)(k*G+g))*CC*DD;
  for (int x=tid;x<CC*DD;x+=256) fo[x]=s_sums[x];
  if (tid<CC){
    size_t o = (size_t)(k*G+g)*CC + tid;
    osxg[o]=s_sxg[tid]; osyg[o]=s_syg[tid]; ocnt[o]=s_cnt[tid];
  }
}

// ---------- 4. deterministic reduce over G partials + centroid update ----------
// fsums physical p = j*256 + m*64 + l ; logical d = 256*j + 4*l + m
__global__ __launch_bounds__(256) void update_kernel(
  const float* __restrict__ fsums, const float* __restrict__ osxg, const float* __restrict__ osyg,
  const int* __restrict__ ocnt, const float* __restrict__ Wp, const float* __restrict__ bp,
  float* __restrict__ cent, int G)
{
  int idx = blockIdx.x*256 + threadIdx.x;   // over K*C*D ; DD%256==0 so (k,c) uniform/block
  int d  = idx % DD;
  int kc = idx / DD;
  int k  = kc / CC, c = kc % CC;
  int j = d >> 8, r = d & 255, l = r >> 2, m = r & 3;
  int p = (j << 8) | (m << 6) | l;
  __shared__ float sX[GMAX], sY[GMAX]; __shared__ int sN[GMAX];
  if (threadIdx.x < G){
    int g = threadIdx.x;
    size_t o = (size_t)(k*G+g)*CC + c;
    sX[g]=osxg[o]; sY[g]=osyg[o]; sN[g]=ocnt[o];
  }
  __syncthreads();
  int n=0; float sx=0.f, sy=0.f;
  for (int t=0;t<G;t++){ n+=sN[t]; sx+=sX[t]; sy+=sY[t]; }
  float s=0.f;
  for (int g=0; g<G; g++)
    s += fsums[((size_t)(k*G+g)*CC + c)*DD + p];
  if (n > 0){
    float nf = (float)n;
    float ts = s + sx*Wp[d] + sy*Wp[DD+d] + nf*bp[d];  // factored posenc re-applied
    cent[(size_t)kc*DD + d] = ts / nf;
  } // else keep old centroid
}

// ---------- 5. MLP ----------
__global__ __launch_bounds__(256) void mlp1_kernel(const float* __restrict__ cent,
  const float* __restrict__ W1, const float* __restrict__ b1, float* __restrict__ h1)
{
  int k = blockIdx.y; int col = blockIdx.x*256 + threadIdx.x;
  __shared__ float srow[CC*DD];
  for (int x=threadIdx.x; x<CC*DD; x+=256) srow[x] = cent[(size_t)k*CC*DD + x];
  __syncthreads();
  float acc[CC];
  #pragma unroll
  for (int r=0;r<CC;r++) acc[r]=0.f;
  for (int dd=0; dd<DD; dd++){
    float wv = W1[(size_t)dd*DD + col];
    #pragma unroll
    for (int r=0;r<CC;r++) acc[r] = fmaf(srow[r*DD+dd], wv, acc[r]);
  }
  float bb = b1[col];
  #pragma unroll
  for (int r=0;r<CC;r++){
    float x = acc[r] + bb;
    h1[((size_t)k*CC+r)*DD + col] = 0.5f*x*(1.f+erff(x*0.70710678118654752440f));
  }
}

__global__ __launch_bounds__(256) void mlp2_kernel(const float* __restrict__ h1,
  const float* __restrict__ W2, const float* __restrict__ b2, float* __restrict__ out)
{
  int k = blockIdx.y; int col = blockIdx.x*256 + threadIdx.x;
  __shared__ float srow[CC*DD];
  for (int x=threadIdx.x; x<CC*DD; x+=256) srow[x] = h1[(size_t)k*CC*DD + x];
  __syncthreads();
  float acc[CC];
  #pragma unroll
  for (int r=0;r<CC;r++) acc[r]=0.f;
  for (int dd=0; dd<DD; dd++){
    float wv = W2[(size_t)dd*DD + col];
    #pragma unroll
    for (int r=0;r<CC;r++) acc[r] = fmaf(srow[r*DD+dd], wv, acc[r]);
  }
  float bb = b2[col];
  #pragma unroll
  for (int r=0;r<CC;r++) out[((size_t)k*CC+r)*DD + col] = acc[r] + bb;
}

// ---------- launch ----------
extern "C" void kernel_launch(void* const* d_in, const int* in_sizes, int n_in,
                              void* d_out, int out_size, void* d_ws, size_t ws_size,
                              hipStream_t stream)
{
  const float* feat = (const float*)d_in[0];
  const float* mask = (const float*)d_in[1];
  const float* boxes= (const float*)d_in[2];
  const float* Wp   = (const float*)d_in[3];
  const float* bp   = (const float*)d_in[4];
  const float* W1   = (const float*)d_in[5];
  const float* b1   = (const float*)d_in[6];
  const float* W2   = (const float*)d_in[7];
  const float* b2   = (const float*)d_in[8];
  const int*   iidx = (const int*)d_in[9];
  const int*   prawh= (const int*)d_in[10];
  const int*   praww= (const int*)d_in[11];
  float* out = (float*)d_out;

  auto align = [](size_t x){ return (x + 255) & ~(size_t)255; };
  int G = GMAX;
  size_t o_cent=0,o_vidx=0,o_vcnt=0,o_scal=0,o_h1=0,o_fs=0,o_sx=0,o_sy=0,o_cn=0,total=0;
  for (;;){
    size_t off = 0;
    o_cent = off; off = align(off + (size_t)KIMG*CC*DD*4);
    o_vidx = off; off = align(off + (size_t)KIMG*NTOK*4);
    o_vcnt = off; off = align(off + (size_t)KIMG*4);
    o_scal = off; off = align(off + (size_t)KIMG*CC*4*4);
    o_h1   = off; off = align(off + (size_t)KIMG*CC*DD*4);
    o_fs   = off; off = align(off + (size_t)KIMG*G*CC*DD*4);
    o_sx   = off; off = align(off + (size_t)KIMG*G*CC*4);
    o_sy   = off; off = align(off + (size_t)KIMG*G*CC*4);
    o_cn   = off; off = align(off + (size_t)KIMG*G*CC*4);
    total = off;
    if (total <= ws_size || G == 1) break;
    G >>= 1;
  }
  char* ws = (char*)d_ws;
  float* cent  = (float*)(ws + o_cent);
  int*   vidx  = (int*)  (ws + o_vidx);
  int*   vcnt  = (int*)  (ws + o_vcnt);
  float* scal  = (float*)(ws + o_scal);
  float* h1    = (float*)(ws + o_h1);
  float* fsums = (float*)(ws + o_fs);
  float* sxg   = (float*)(ws + o_sx);
  float* syg   = (float*)(ws + o_sy);
  int*   ocnt  = (int*)  (ws + o_cn);

  compact_kernel<<<KIMG,256,0,stream>>>(mask, vidx, vcnt);
  init_kernel<<<KIMG,256,0,stream>>>(feat, boxes, Wp, bp, iidx, prawh, praww, cent);
  scalar_kernel<<<dim3(CC,KIMG),64,0,stream>>>(cent, Wp, bp, scal);
  for (int it=0; it<NITER; ++it){
    assign_kernel<<<dim3(G,KIMG),256,0,stream>>>(feat, boxes, prawh, praww,
        cent, scal, vidx, vcnt, fsums, sxg, syg, ocnt, G);
    update_kernel<<<(KIMG*CC*DD)/256,256,0,stream>>>(fsums, sxg, syg, ocnt, Wp, bp, cent, G);
    scalar_kernel<<<dim3(CC,KIMG),64,0,stream>>>(cent, Wp, bp, scal);
  }
  mlp1_kernel<<<dim3(3,KIMG),256,0,stream>>>(cent, W1, b1, h1);
  mlp2_kernel<<<dim3(3,KIMG),256,0,stream>>>(h1, W2, b2, out);
}

// Round 5
// 2068.398 us; speedup vs baseline: 1.0278x; 1.0278x over previous
//
#include <hip/hip_runtime.h>
#include <hip/hip_bf16.h>
#include <math.h>

#define KIMG 8
#define HH 128
#define WW 128
#define NTOK (HH*WW)
#define DD 768
#define CC 10
#define NITER 5
#define GMAX 64

// ---------- wave helpers ----------
__device__ __forceinline__ float rl63(float x){
  return __int_as_float(__builtin_amdgcn_readlane(__float_as_int(x), 63));
}
__device__ __forceinline__ float rfl_f(float x){
  return __int_as_float(__builtin_amdgcn_readfirstlane(__float_as_int(x)));
}
template<int CTRL,int RMASK>
__device__ __forceinline__ float dppadd(float x){
  // compiler-managed DPP (hazard-safe): mov_dpp + add
  int y = __builtin_amdgcn_update_dpp(0, __float_as_int(x), CTRL, RMASK, 0xf, true);
  return x + __int_as_float(y);
}
// full-wave sum; total lands in lane 63 (row_shr 1,2,4,8 then bcast15, bcast31)
__device__ __forceinline__ float wredsum(float x){
  x = dppadd<0x111,0xf>(x);
  x = dppadd<0x112,0xf>(x);
  x = dppadd<0x114,0xf>(x);
  x = dppadd<0x118,0xf>(x);
  x = dppadd<0x142,0xa>(x);
  x = dppadd<0x143,0xc>(x);
  return x;
}
__device__ __forceinline__ float read_dim_f(const int* p){
  int v = *p;
  if (v > 0 && v < (1<<20)) return (float)v;   // plausible integer
  return __int_as_float(v);                    // else float bits
}

union F4 { float4 v; float f[4]; };

// ---------- 1. compact valid token indices (deterministic order) ----------
__global__ __launch_bounds__(256) void compact_kernel(const float* __restrict__ mask,
    int* __restrict__ vidx, int* __restrict__ vcnt){
  int k = blockIdx.x, tid = threadIdx.x;
  __shared__ int s[256];
  const float* mk = mask + (size_t)k*NTOK;
  int base = tid*64, c = 0;
  for (int j=0;j<64;j++) c += (mk[base+j] > 0.f) ? 1 : 0;
  s[tid] = c; __syncthreads();
  for (int st=1; st<256; st<<=1){
    int v = s[tid]; int u = (tid>=st) ? s[tid-st] : 0;
    __syncthreads(); s[tid] = v+u; __syncthreads();
  }
  int off = s[tid] - c;          // exclusive prefix
  if (tid==255) vcnt[k] = s[255];
  int* vk = vidx + (size_t)k*NTOK;
  for (int j=0;j<64;j++){ if (mk[base+j] > 0.f) vk[off++] = base+j; }
}

// ---------- 2. initial centroids = tokens[init_idx] ----------
__global__ __launch_bounds__(256) void init_kernel(const float* __restrict__ feat,
  const float* __restrict__ boxes, const float* __restrict__ Wp, const float* __restrict__ bp,
  const int* __restrict__ iidx, const int* __restrict__ prawh, const int* __restrict__ praww,
  float* __restrict__ cent){
  int k = blockIdx.x, tid = threadIdx.x;
  float top = boxes[k*4+0], lft = boxes[k*4+1], bot = boxes[k*4+2], rgt = boxes[k*4+3];
  float rh = read_dim_f(prawh), rw = read_dim_f(praww);
  float inv_rw = 1.f/(rw-1.f), inv_rh = 1.f/(rh-1.f);
  float xs = (rgt-lft)*(1.f/(float)WW), ys = (bot-top)*(1.f/(float)HH);
  for (int c=0;c<CC;c++){
    int tok = iidx[k*CC+c];
    int h = tok>>7, w = tok&127;
    float xg = fminf(fmaxf(((float)w*xs+lft)*inv_rw,0.f),1.f);
    float yg = fminf(fmaxf(((float)h*ys+top)*inv_rh,0.f),1.f);
    const float* fp = feat + ((size_t)k*NTOK + tok)*DD;
    float* cp = cent + ((size_t)k*CC + c)*DD;
    for (int d=tid; d<DD; d+=256)
      cp[d] = fp[d] + xg*Wp[d] + yg*Wp[DD+d] + bp[d];
  }
}

// ---------- 2b. per-cluster scalars: sA=||c||^2-2bp.c, sW0=-2Wp0.c, sW1=-2Wp1.c ----------
__global__ __launch_bounds__(64) void scalar_kernel(const float* __restrict__ cent,
  const float* __restrict__ Wp, const float* __restrict__ bp, float* __restrict__ scal){
  int c = blockIdx.x, k = blockIdx.y, lane = threadIdx.x;
  const float* cp = cent + ((size_t)k*CC+c)*DD;
  float a0=0.f,a1=0.f,ab=0.f,an=0.f;
  #pragma unroll
  for (int j=0;j<12;j++){
    float cv = cp[j*64+lane];
    a0=fmaf(cv,Wp[j*64+lane],a0);
    a1=fmaf(cv,Wp[DD+j*64+lane],a1);
    ab=fmaf(cv,bp[j*64+lane],ab);
    an=fmaf(cv,cv,an);
  }
  a0=wredsum(a0); a1=wredsum(a1); ab=wredsum(ab); an=wredsum(an);
  if (lane==63){
    float* o = scal + ((size_t)k*CC+c)*4;
    o[0]=fmaf(-2.f,ab,an); o[1]=-2.f*a0; o[2]=-2.f*a1; o[3]=0.f;
  }
}

// ---------- 3. assignment + per-block partial sums (hot) ----------
// 512 threads (8 waves). lane owns dims d = 256*j + 4*lane + m.
// Centroids staged in LDS pre-scaled by -2 (exact power-of-2 scale, rounding-
// identical scores); c-outer/t-inner keeps the live register set ~95 VGPRs.
// Per-cluster scalars live in SGPRs (readfirstlane). G=64 -> 512 blocks = 2/CU.
__global__ __launch_bounds__(512,4) void assign_kernel(
    const float* __restrict__ feat, const float* __restrict__ boxes,
    const int* __restrict__ prawh, const int* __restrict__ praww,
    const float* __restrict__ cent, const float* __restrict__ scal,
    const int* __restrict__ vidx, const int* __restrict__ vcnt,
    float* __restrict__ fsums, float* __restrict__ osxg, float* __restrict__ osyg,
    int* __restrict__ ocnt, int G)
{
  int g = blockIdx.x, k = blockIdx.y;
  int tid = threadIdx.x, lane = tid & 63, wv = tid >> 6;
  __shared__ float s_cent[CC*DD];
  __shared__ float s_sums[CC*DD];
  __shared__ float s_sxg[16], s_syg[16];
  __shared__ int   s_cnt[16];
  const float* ck = cent + (size_t)k*CC*DD;
  for (int x=tid;x<CC*DD;x+=512){ s_cent[x] = -2.f*ck[x]; s_sums[x]=0.f; }
  if (tid<16){ s_sxg[tid]=0.f; s_syg[tid]=0.f; s_cnt[tid]=0; }
  __syncthreads();

  // per-cluster scalars -> SGPRs (wave-uniform)
  float sA[CC], sW0[CC], sW1[CC];
  #pragma unroll
  for (int c=0;c<CC;c++){
    F4 sv; sv.v = *(const float4*)(scal + ((size_t)k*CC+c)*4);
    sA[c]=rfl_f(sv.f[0]); sW0[c]=rfl_f(sv.f[1]); sW1[c]=rfl_f(sv.f[2]);
  }

  float top=rfl_f(boxes[k*4+0]), lft=rfl_f(boxes[k*4+1]);
  float bot=rfl_f(boxes[k*4+2]), rgt=rfl_f(boxes[k*4+3]);
  float rh = read_dim_f(prawh), rw = read_dim_f(praww);
  float inv_rw = 1.f/(rw-1.f), inv_rh = 1.f/(rh-1.f);
  float xs = (rgt-lft)*(1.f/(float)WW), ys = (bot-top)*(1.f/(float)HH);

  int count = vcnt[k];
  int nw = G*8;
  int wid = g*8 + wv;
  int cbeg = (int)(((long long)count * wid) / nw);
  int cend = (int)(((long long)count * (wid+1)) / nw);
  const int* vk = vidx + (size_t)k*NTOK;
  const float* featk = feat + (size_t)k*NTOK*DD;

  for (int seg = cbeg; seg < cend; seg += 64){
    int nseg = min(64, cend - seg);
    int vkq = vk[seg + min(lane, nseg-1)];   // wave's token indices, lane-held

    for (int q=0; q<nseg; q+=4){
      int tok[4];
      F4 buf[4][3];
      float xg[4], yg[4];
      #pragma unroll
      for (int t=0;t<4;t++){
        int ridx = min(q+t, nseg-1);
        tok[t] = __builtin_amdgcn_readlane(vkq, ridx);     // SGPR token index
        const float* fp = featk + (size_t)tok[t]*DD + 4*lane;
        buf[t][0].v = *(const float4*)(fp);
        buf[t][1].v = *(const float4*)(fp+256);
        buf[t][2].v = *(const float4*)(fp+512);
        int h = tok[t]>>7, w = tok[t]&127;
        xg[t] = fminf(fmaxf(((float)w*xs+lft)*inv_rw,0.f),1.f);
        yg[t] = fminf(fmaxf(((float)h*ys+top)*inv_rh,0.f),1.f);
      }

      float best[4]; int bl[4];
      #pragma unroll
      for (int t=0;t<4;t++){ best[t]=3.4e38f; bl[t]=0; }

      #pragma unroll
      for (int c=0;c<CC;c++){
        F4 cs0, cs1, cs2;                     // (-2*cent) slice, shared by 4 tokens
        const float* cp = s_cent + c*DD + 4*lane;
        cs0.v = *(const float4*)(cp);
        cs1.v = *(const float4*)(cp+256);
        cs2.v = *(const float4*)(cp+512);
        #pragma unroll
        for (int t=0;t<4;t++){
          float acc = 0.f;
          #pragma unroll
          for (int m=0;m<4;m++){
            acc = fmaf(buf[t][0].f[m], cs0.f[m], acc);
            acc = fmaf(buf[t][1].f[m], cs1.f[m], acc);
            acc = fmaf(buf[t][2].f[m], cs2.f[m], acc);
          }
          acc = wredsum(acc);
          float dot = rl63(acc);              // = -2 * (t . c), uniform
          float sc = fmaf(xg[t],sW0[c], fmaf(yg[t],sW1[c], sA[c])) + dot;
          if (sc < best[t]){ best[t]=sc; bl[t]=c; }
        }
      }

      #pragma unroll
      for (int t=0;t<4;t++){
        int b = __builtin_amdgcn_readfirstlane(bl[t]);
        if (q+t < nseg){                      // uniform predicate
          float* sb = s_sums + b*DD + lane;   // physical p = j*256+m*64+lane
          #pragma unroll
          for (int j=0;j<3;j++)
            #pragma unroll
            for (int m=0;m<4;m++)
              atomicAdd(&sb[j*256 + m*64], buf[t][j].f[m]);
          if (lane==0){
            atomicAdd(&s_cnt[b],1);
            atomicAdd(&s_sxg[b],xg[t]);
            atomicAdd(&s_syg[b],yg[t]);
          }
        }
      }
    }
  }
  __syncthreads();

  float* fo = fsums + ((size_t)(k*G+g))*CC*DD;
  for (int x=tid;x<CC*DD;x+=512) fo[x]=s_sums[x];
  if (tid<CC){
    size_t o = (size_t)(k*G+g)*CC + tid;
    osxg[o]=s_sxg[tid]; osyg[o]=s_syg[tid]; ocnt[o]=s_cnt[tid];
  }
}

// ---------- 4. deterministic reduce over G partials + centroid update ----------
// fsums physical p = j*256 + m*64 + l ; logical d = 256*j + 4*l + m
__global__ __launch_bounds__(256) void update_kernel(
  const float* __restrict__ fsums, const float* __restrict__ osxg, const float* __restrict__ osyg,
  const int* __restrict__ ocnt, const float* __restrict__ Wp, const float* __restrict__ bp,
  float* __restrict__ cent, int G)
{
  int idx = blockIdx.x*256 + threadIdx.x;   // over K*C*D ; DD%256==0 so (k,c) uniform/block
  int d  = idx % DD;
  int kc = idx / DD;
  int k  = kc / CC, c = kc % CC;
  int j = d >> 8, r = d & 255, l = r >> 2, m = r & 3;
  int p = (j << 8) | (m << 6) | l;
  __shared__ float sX[GMAX], sY[GMAX]; __shared__ int sN[GMAX];
  if (threadIdx.x < G){
    int g = threadIdx.x;
    size_t o = (size_t)(k*G+g)*CC + c;
    sX[g]=osxg[o]; sY[g]=osyg[o]; sN[g]=ocnt[o];
  }
  __syncthreads();
  int n=0; float sx=0.f, sy=0.f;
  for (int t=0;t<G;t++){ n+=sN[t]; sx+=sX[t]; sy+=sY[t]; }
  float s=0.f;
  for (int g=0; g<G; g++)
    s += fsums[((size_t)(k*G+g)*CC + c)*DD + p];
  if (n > 0){
    float nf = (float)n;
    float ts = s + sx*Wp[d] + sy*Wp[DD+d] + nf*bp[d];  // factored posenc re-applied
    cent[(size_t)kc*DD + d] = ts / nf;
  } // else keep old centroid
}

// ---------- 5. MLP ----------
__global__ __launch_bounds__(256) void mlp1_kernel(const float* __restrict__ cent,
  const float* __restrict__ W1, const float* __restrict__ b1, float* __restrict__ h1)
{
  int k = blockIdx.y; int col = blockIdx.x*256 + threadIdx.x;
  __shared__ float srow[CC*DD];
  for (int x=threadIdx.x; x<CC*DD; x+=256) srow[x] = cent[(size_t)k*CC*DD + x];
  __syncthreads();
  float acc[CC];
  #pragma unroll
  for (int r=0;r<CC;r++) acc[r]=0.f;
  for (int dd=0; dd<DD; dd++){
    float wv = W1[(size_t)dd*DD + col];
    #pragma unroll
    for (int r=0;r<CC;r++) acc[r] = fmaf(srow[r*DD+dd], wv, acc[r]);
  }
  float bb = b1[col];
  #pragma unroll
  for (int r=0;r<CC;r++){
    float x = acc[r] + bb;
    h1[((size_t)k*CC+r)*DD + col] = 0.5f*x*(1.f+erff(x*0.70710678118654752440f));
  }
}

__global__ __launch_bounds__(256) void mlp2_kernel(const float* __restrict__ h1,
  const float* __restrict__ W2, const float* __restrict__ b2, float* __restrict__ out)
{
  int k = blockIdx.y; int col = blockIdx.x*256 + threadIdx.x;
  __shared__ float srow[CC*DD];
  for (int x=threadIdx.x; x<CC*DD; x+=256) srow[x] = h1[(size_t)k*CC*DD + x];
  __syncthreads();
  float acc[CC];
  #pragma unroll
  for (int r=0;r<CC;r++) acc[r]=0.f;
  for (int dd=0; dd<DD; dd++){
    float wv = W2[(size_t)dd*DD + col];
    #pragma unroll
    for (int r=0;r<CC;r++) acc[r] = fmaf(srow[r*DD+dd], wv, acc[r]);
  }
  float bb2 = b2[col];
  #pragma unroll
  for (int r=0;r<CC;r++) out[((size_t)k*CC+r)*DD + col] = acc[r] + bb2;
}

// ---------- launch ----------
extern "C" void kernel_launch(void* const* d_in, const int* in_sizes, int n_in,
                              void* d_out, int out_size, void* d_ws, size_t ws_size,
                              hipStream_t stream)
{
  const float* feat = (const float*)d_in[0];
  const float* mask = (const float*)d_in[1];
  const float* boxes= (const float*)d_in[2];
  const float* Wp   = (const float*)d_in[3];
  const float* bp   = (const float*)d_in[4];
  const float* W1   = (const float*)d_in[5];
  const float* b1   = (const float*)d_in[6];
  const float* W2   = (const float*)d_in[7];
  const float* b2   = (const float*)d_in[8];
  const int*   iidx = (const int*)d_in[9];
  const int*   prawh= (const int*)d_in[10];
  const int*   praww= (const int*)d_in[11];
  float* out = (float*)d_out;

  auto align = [](size_t x){ return (x + 255) & ~(size_t)255; };
  int G = GMAX;
  size_t o_cent=0,o_vidx=0,o_vcnt=0,o_scal=0,o_h1=0,o_fs=0,o_sx=0,o_sy=0,o_cn=0,total=0;
  for (;;){
    size_t off = 0;
    o_cent = off; off = align(off + (size_t)KIMG*CC*DD*4);
    o_vidx = off; off = align(off + (size_t)KIMG*NTOK*4);
    o_vcnt = off; off = align(off + (size_t)KIMG*4);
    o_scal = off; off = align(off + (size_t)KIMG*CC*4*4);
    o_h1   = off; off = align(off + (size_t)KIMG*CC*DD*4);
    o_fs   = off; off = align(off + (size_t)KIMG*G*CC*DD*4);
    o_sx   = off; off = align(off + (size_t)KIMG*G*CC*4);
    o_sy   = off; off = align(off + (size_t)KIMG*G*CC*4);
    o_cn   = off; off = align(off + (size_t)KIMG*G*CC*4);
    total = off;
    if (total <= ws_size || G == 1) break;
    G >>= 1;
  }
  char* ws = (char*)d_ws;
  float* cent  = (float*)(ws + o_cent);
  int*   vidx  = (int*)  (ws + o_vidx);
  int*   vcnt  = (int*)  (ws + o_vcnt);
  float* scal  = (float*)(ws + o_scal);
  float* h1    = (float*)(ws + o_h1);
  float* fsums = (float*)(ws + o_fs);
  float* sxg   = (float*)(ws + o_sx);
  float* syg   = (float*)(ws + o_sy);
  int*   ocnt  = (int*)  (ws + o_cn);

  compact_kernel<<<KIMG,256,0,stream>>>(mask, vidx, vcnt);
  init_kernel<<<KIMG,256,0,stream>>>(feat, boxes, Wp, bp, iidx, prawh, praww, cent);
  scalar_kernel<<<dim3(CC,KIMG),64,0,stream>>>(cent, Wp, bp, scal);
  for (int it=0; it<NITER; ++it){
    assign_kernel<<<dim3(G,KIMG),512,0,stream>>>(feat, boxes, prawh, praww,
        cent, scal, vidx, vcnt, fsums, sxg, syg, ocnt, G);
    update_kernel<<<(KIMG*CC*DD)/256,256,0,stream>>>(fsums, sxg, syg, ocnt, Wp, bp, cent, G);
    scalar_kernel<<<dim3(CC,KIMG),64,0,stream>>>(cent, Wp, bp, scal);
  }
  mlp1_kernel<<<dim3(3,KIMG),256,0,stream>>>(cent, W1, b1, h1);
  mlp2_kernel<<<dim3(3,KIMG),256,0,stream>>>(h1, W2, b2, out);
}